// Round 1
// baseline (269.000 us; speedup 1.0000x reference)
//
#include <hip/hip_runtime.h>

// CalculateSLayer: A = adj[:,:,0]+adj[:,:,1]  (L x L, L=4096)
//   h_in  = A^T @ h   (output 0)
//   h_out = A   @ h   (output 1)
// Strategy: single pass over adj (134 MB). Each block stages a 128x128 fp16
// tile of A in LDS twice (normal + transposed), runs mfma_f32_16x16x32_f16
// against an L2-resident transposed fp16 copy of h (built by prep kernel into
// d_ws), and atomically accumulates fp32 partials into both outputs.

typedef _Float16 half8 __attribute__((ext_vector_type(8)));
typedef float f32x4 __attribute__((ext_vector_type(4)));

#define LL 4096
#define DD 150
#define DPAD 160
#define BT 128
#define TSTR_B 272              // LDS bytes per row (136 halfs): 16B-aligned, bank-spread
#define TT_OFF (128 * TSTR_B)   // transposed tile offset

// Builds HT[d][row] = (fp16) h[row][d] for d<150, 0 for 150<=d<160; zeroes out.
__global__ __launch_bounds__(256) void prep_kernel(const float* __restrict__ h,
                                                   _Float16* __restrict__ HT,
                                                   float* __restrict__ out) {
    const int idx = blockIdx.x * 256 + threadIdx.x;   // grid covers 2*L*DD = 1228800
    if (idx < DPAD * LL) {
        const int d = idx >> 12;          // / 4096
        const int j = idx & (LL - 1);
        const float v = (d < DD) ? h[(size_t)j * DD + d] : 0.0f;
        HT[idx] = (_Float16)v;
    }
    if (idx < 2 * LL * DD) out[idx] = 0.0f;
}

__global__ __launch_bounds__(256) void fused_kernel(const float* __restrict__ adj,
                                                    const _Float16* __restrict__ HT,
                                                    float* __restrict__ out) {
    __shared__ __align__(16) unsigned char smem[2 * 128 * TSTR_B];  // T + Tt = 69632 B
    const int tid = threadIdx.x;
    const int wave = tid >> 6, lane = tid & 63;
    const int it = blockIdx.x >> 5, jt = blockIdx.x & 31;
    const int i0 = it * BT, j0 = jt * BT;

    // ---- stage: T[ii][jj] and Tt[jj][ii] as fp16 (sum of 2 edge channels) ----
    // Each wave-load grabs one full tile row (64 lanes x float4 = 1 KB = 128 j x 2 ch).
    for (int itr = 0; itr < 8; ++itr) {
        const int ii0 = (wave * 8 + itr) * 4;   // 4-row group
        _Float16 s0[4], s1[4];
#pragma unroll
        for (int rr = 0; rr < 4; ++rr) {
            const float4 v = *(const float4*)(adj + (size_t)(i0 + ii0 + rr) * (2 * LL)
                                              + (size_t)j0 * 2 + lane * 4);
            s0[rr] = (_Float16)(v.x + v.y);     // jj = 2*lane
            s1[rr] = (_Float16)(v.z + v.w);     // jj = 2*lane + 1
            union { _Float16 hh[2]; unsigned int u; } p;
            p.hh[0] = s0[rr]; p.hh[1] = s1[rr];
            *(unsigned int*)(smem + (ii0 + rr) * TSTR_B + lane * 4) = p.u;
        }
        union { _Float16 hh[4]; unsigned long long u; } c0, c1;
#pragma unroll
        for (int rr = 0; rr < 4; ++rr) { c0.hh[rr] = s0[rr]; c1.hh[rr] = s1[rr]; }
        *(unsigned long long*)(smem + TT_OFF + (2 * lane) * TSTR_B + ii0 * 2) = c0.u;
        *(unsigned long long*)(smem + TT_OFF + (2 * lane + 1) * TSTR_B + ii0 * 2) = c1.u;
    }
    __syncthreads();

    const int r = lane & 15, g = lane >> 4;
    // ph=0: h_out partial = T  @ h[j0-range]  -> rows i0+..., out offset L*DD
    // ph=1: h_in  partial = Tt @ h[i0-range]  -> rows j0+..., out offset 0
#pragma unroll
    for (int ph = 0; ph < 2; ++ph) {
        const unsigned char* Abase = smem + (ph ? TT_OFF : 0);
        const int cbase = ph ? i0 : j0;          // HT column base (= K rows of B)
        const int obase = ph ? j0 : i0;          // output row base
        float* outp = out + (ph ? 0 : (size_t)LL * DD);
        const int m0 = wave * 2, m1 = wave * 2 + 1;   // M-tiles owned by this wave

        f32x4 acc0[10], acc1[10];
#pragma unroll
        for (int nt = 0; nt < 10; ++nt) {
            acc0[nt] = (f32x4){0.f, 0.f, 0.f, 0.f};
            acc1[nt] = (f32x4){0.f, 0.f, 0.f, 0.f};
        }
#pragma unroll
        for (int k = 0; k < 4; ++k) {
            const half8 a0 = *(const half8*)(Abase + (m0 * 16 + r) * TSTR_B + k * 64 + g * 16);
            const half8 a1 = *(const half8*)(Abase + (m1 * 16 + r) * TSTR_B + k * 64 + g * 16);
#pragma unroll
            for (int nt = 0; nt < 10; ++nt) {
                const half8 b = *(const half8*)(HT + (size_t)(nt * 16 + r) * LL
                                                + cbase + k * 32 + g * 8);
                acc0[nt] = __builtin_amdgcn_mfma_f32_16x16x32_f16(a0, b, acc0[nt], 0, 0, 0);
                acc1[nt] = __builtin_amdgcn_mfma_f32_16x16x32_f16(a1, b, acc1[nt], 0, 0, 0);
            }
        }
        // D layout: row = 4*g + q (within 16-tile), col = r  (m89/m91-verified)
#pragma unroll
        for (int nt = 0; nt < 10; ++nt) {
            const int d = nt * 16 + r;
            if (d < DD) {
                const int row0 = obase + m0 * 16 + g * 4;
                const int row1 = obase + m1 * 16 + g * 4;
#pragma unroll
                for (int q = 0; q < 4; ++q) {
                    unsafeAtomicAdd(&outp[(size_t)(row0 + q) * DD + d], acc0[nt][q]);
                    unsafeAtomicAdd(&outp[(size_t)(row1 + q) * DD + d], acc1[nt][q]);
                }
            }
        }
    }
}

extern "C" void kernel_launch(void* const* d_in, const int* in_sizes, int n_in,
                              void* d_out, int out_size, void* d_ws, size_t ws_size,
                              hipStream_t stream) {
    const float* adj = (const float*)d_in[0];   // [4096, 4096, 2] fp32
    const float* h   = (const float*)d_in[1];   // [4096, 150] fp32
    float* out = (float*)d_out;                  // [h_in | h_out], each 4096*150 fp32
    _Float16* HT = (_Float16*)d_ws;              // [160][4096] fp16 transposed h

    hipLaunchKernelGGL(prep_kernel, dim3((2 * LL * DD) / 256), dim3(256), 0, stream,
                       h, HT, out);
    hipLaunchKernelGGL(fused_kernel, dim3((LL / BT) * (LL / BT)), dim3(256), 0, stream,
                       adj, HT, out);
}

// Round 2
// 124.501 us; speedup vs baseline: 2.1606x; 2.1606x over previous
//
#include <hip/hip_runtime.h>

// CalculateSLayer: A = adj[:,:,0]+adj[:,:,1]  (L x L, L=4096)
//   h_in  = A^T @ h   (output 0, rows j)
//   h_out = A   @ h   (output 1, rows i)
// Round 2: no atomics. Two GEMM kernels, each block owns full K for its
// 16 output rows. hout reads A row-major straight from global (barrier-free
// K-loop); hin transposes 256x16 column chunks through double-buffered LDS.
// B-operand = HT (fp16 transposed h, built by prep into d_ws), MFMA
// f32_16x16x32_f16, cross-wave K-reduce via LDS at block end.

typedef _Float16 half8 __attribute__((ext_vector_type(8)));
typedef float f32x4 __attribute__((ext_vector_type(4)));

#define LL 4096
#define DD 150
#define DPAD 160
#define BSTR 264   // halfs per Tt row: 256 + 8 pad (528 B, 16B-aligned rows)

// HT[d][j] = (fp16) h[j][d], zero-padded for 150<=d<160.
__global__ __launch_bounds__(256) void prep_kernel(const float* __restrict__ h,
                                                   _Float16* __restrict__ HT) {
    const int idx = blockIdx.x * 256 + threadIdx.x;   // grid covers DPAD*LL
    const int d = idx >> 12;
    const int j = idx & (LL - 1);
    HT[idx] = (d < DD) ? (_Float16)h[(size_t)j * DD + d] : (_Float16)0.0f;
}

// h_out = A @ h : block owns rows i0..i0+15, full K. 512 threads = 8 waves,
// wave w reduces K in [w*512, w*512+512).
__global__ __launch_bounds__(512) void hout_kernel(const float* __restrict__ adj,
                                                   const _Float16* __restrict__ HT,
                                                   float* __restrict__ out) {
    __shared__ float red[8][16][DPAD];   // 80 KB
    const int tid = threadIdx.x;
    const int wave = tid >> 6, lane = tid & 63;
    const int r = lane & 15, g = lane >> 4;
    const int i0 = blockIdx.x * 16;

    f32x4 acc[10];
#pragma unroll
    for (int nt = 0; nt < 10; ++nt) acc[nt] = (f32x4){0.f, 0.f, 0.f, 0.f};

    const float* arow = adj + (size_t)(i0 + r) * (2 * LL);
#pragma unroll 2
    for (int c = 0; c < 16; ++c) {
        const int k0 = wave * 512 + c * 32;
        const float4* ap = (const float4*)(arow + (size_t)(k0 + g * 8) * 2);
        const float4 q0 = ap[0], q1 = ap[1], q2 = ap[2], q3 = ap[3];
        half8 a;
        a[0] = (_Float16)(q0.x + q0.y); a[1] = (_Float16)(q0.z + q0.w);
        a[2] = (_Float16)(q1.x + q1.y); a[3] = (_Float16)(q1.z + q1.w);
        a[4] = (_Float16)(q2.x + q2.y); a[5] = (_Float16)(q2.z + q2.w);
        a[6] = (_Float16)(q3.x + q3.y); a[7] = (_Float16)(q3.z + q3.w);
#pragma unroll
        for (int nt = 0; nt < 10; ++nt) {
            const half8 b = *(const half8*)(HT + (size_t)(nt * 16 + r) * LL + k0 + g * 8);
            acc[nt] = __builtin_amdgcn_mfma_f32_16x16x32_f16(a, b, acc[nt], 0, 0, 0);
        }
    }
    // cross-wave reduce: D layout row=g*4+q, col=r (verified round 1)
#pragma unroll
    for (int nt = 0; nt < 10; ++nt)
#pragma unroll
        for (int q = 0; q < 4; ++q)
            red[wave][g * 4 + q][nt * 16 + r] = acc[nt][q];
    __syncthreads();
    for (int e = tid; e < 16 * DPAD; e += 512) {
        const int row = e / DPAD, d = e % DPAD;
        float s = 0.f;
#pragma unroll
        for (int w = 0; w < 8; ++w) s += red[w][row][d];
        if (d < DD) out[(size_t)LL * DD + (size_t)(i0 + row) * DD + d] = s;
    }
}

// h_in = A^T @ h : block owns columns j0..j0+15, full K (= i). Column strip
// transposed through double-buffered LDS in 256-row chunks.
__global__ __launch_bounds__(512) void hin_kernel(const float* __restrict__ adj,
                                                  const _Float16* __restrict__ HT,
                                                  float* __restrict__ out) {
    __shared__ _Float16 Tt[2][16][BSTR];  // 16.5 KB: Tt[buf][j_local][i_local]
    __shared__ float red[8][16][DPAD];    // 80 KB
    const int tid = threadIdx.x;
    const int wave = tid >> 6, lane = tid & 63;
    const int r = lane & 15, g = lane >> 4;
    const int j0 = blockIdx.x * 16;
    const int lrow = tid >> 1, lhalf = tid & 1;  // staging: 64 B per thread

    f32x4 acc[10];
#pragma unroll
    for (int nt = 0; nt < 10; ++nt) acc[nt] = (f32x4){0.f, 0.f, 0.f, 0.f};

    const float* abase = adj + (size_t)j0 * 2 + (size_t)lhalf * 16;
    float4 q0, q1, q2, q3;
    {   // prologue: stage chunk 0
        const float4* ap = (const float4*)(abase + (size_t)lrow * (2 * LL));
        q0 = ap[0]; q1 = ap[1]; q2 = ap[2]; q3 = ap[3];
        _Float16 s[8] = {(_Float16)(q0.x + q0.y), (_Float16)(q0.z + q0.w),
                         (_Float16)(q1.x + q1.y), (_Float16)(q1.z + q1.w),
                         (_Float16)(q2.x + q2.y), (_Float16)(q2.z + q2.w),
                         (_Float16)(q3.x + q3.y), (_Float16)(q3.z + q3.w)};
#pragma unroll
        for (int jj = 0; jj < 8; ++jj) Tt[0][lhalf * 8 + jj][lrow] = s[jj];
    }
#pragma unroll
    for (int c = 0; c < 16; ++c) {
        __syncthreads();   // Tt[c&1] ready; prev reads of Tt[(c+1)&1] done
        if (c < 15) {
            const float4* ap = (const float4*)(abase + (size_t)((c + 1) * 256 + lrow) * (2 * LL));
            q0 = ap[0]; q1 = ap[1]; q2 = ap[2]; q3 = ap[3];
        }
        const int buf = c & 1;
        const half8 a = *(const half8*)(&Tt[buf][r][wave * 32 + g * 8]);
#pragma unroll
        for (int nt = 0; nt < 10; ++nt) {
            const half8 b = *(const half8*)(HT + (size_t)(nt * 16 + r) * LL
                                            + c * 256 + wave * 32 + g * 8);
            acc[nt] = __builtin_amdgcn_mfma_f32_16x16x32_f16(a, b, acc[nt], 0, 0, 0);
        }
        if (c < 15) {
            _Float16 s[8] = {(_Float16)(q0.x + q0.y), (_Float16)(q0.z + q0.w),
                             (_Float16)(q1.x + q1.y), (_Float16)(q1.z + q1.w),
                             (_Float16)(q2.x + q2.y), (_Float16)(q2.z + q2.w),
                             (_Float16)(q3.x + q3.y), (_Float16)(q3.z + q3.w)};
#pragma unroll
            for (int jj = 0; jj < 8; ++jj) Tt[buf ^ 1][lhalf * 8 + jj][lrow] = s[jj];
        }
    }
#pragma unroll
    for (int nt = 0; nt < 10; ++nt)
#pragma unroll
        for (int q = 0; q < 4; ++q)
            red[wave][g * 4 + q][nt * 16 + r] = acc[nt][q];
    __syncthreads();
    for (int e = tid; e < 16 * DPAD; e += 512) {
        const int row = e / DPAD, d = e % DPAD;
        float s = 0.f;
#pragma unroll
        for (int w = 0; w < 8; ++w) s += red[w][row][d];
        if (d < DD) out[(size_t)(j0 + row) * DD + d] = s;
    }
}

extern "C" void kernel_launch(void* const* d_in, const int* in_sizes, int n_in,
                              void* d_out, int out_size, void* d_ws, size_t ws_size,
                              hipStream_t stream) {
    const float* adj = (const float*)d_in[0];   // [4096, 4096, 2] fp32
    const float* h   = (const float*)d_in[1];   // [4096, 150] fp32
    float* out = (float*)d_out;                  // [h_in | h_out] fp32
    _Float16* HT = (_Float16*)d_ws;              // [160][4096] fp16

    hipLaunchKernelGGL(prep_kernel, dim3((DPAD * LL) / 256), dim3(256), 0, stream, h, HT);
    hipLaunchKernelGGL(hout_kernel, dim3(LL / 16), dim3(512), 0, stream, adj, HT, out);
    hipLaunchKernelGGL(hin_kernel,  dim3(LL / 16), dim3(512), 0, stream, adj, HT, out);
}